// Round 9
// baseline (153.364 us; speedup 1.0000x reference)
//
#include <hip/hip_runtime.h>
#include <hip/hip_bf16.h>
#include <math.h>

#define NN 768
#define DD 64
#define SS 32
#define PP 4
#define NB2 1536   // k2 grid

#define MU_STEP   (12.0f / 31.0f)
#define INV2SIG2  3.55555555555f
#define NEG2C     (-INV2SIG2 * 1.4426950408889634f)

typedef __attribute__((ext_vector_type(8))) short bf16x8;
typedef __attribute__((ext_vector_type(4))) float f32x4;

__device__ __forceinline__ unsigned short f2bf(float f) {
    unsigned u = __float_as_uint(f);
    u += 0x7FFFu + ((u >> 16) & 1u);           // RNE
    return (unsigned short)(u >> 16);
}
__device__ __forceinline__ float bf2f(unsigned short b) {
    return __uint_as_float(((unsigned)b) << 16);
}

// ---------------------------------------------------------------------------
// kD6 (grid=6144, 128 thr): b = p*1536 + x*2 + h  ->  XCD(b) = (2x+h)%8,
// the SAME XCD as k2 consumer block bid = 2x+h. Writes dG[p][x][h*384..+384).
// Block 0 zeroes the last-block counter.
// ---------------------------------------------------------------------------
__global__ __launch_bounds__(128) void kD6(const float* __restrict__ coords,
                                           float* __restrict__ dG,
                                           unsigned* __restrict__ ctr) {
    const int b = blockIdx.x;
    if (b == 0 && threadIdx.x == 0) *ctr = 0u;
    const int p  = b / NB2;
    const int xh = b - p * NB2;
    const int x  = xh >> 1;
    const int h  = xh & 1;
    const float cxx = coords[((size_t)p * NN + x) * 3 + 0];
    const float cxy = coords[((size_t)p * NN + x) * 3 + 1];
    const float cxz = coords[((size_t)p * NN + x) * 3 + 2];
#pragma unroll
    for (int yb = 0; yb < 3; ++yb) {
        const int y = h * 384 + yb * 128 + threadIdx.x;
        const float dx = cxx - coords[((size_t)p * NN + y) * 3 + 0];
        const float dy = cxy - coords[((size_t)p * NN + y) * 3 + 1];
        const float dz = cxz - coords[((size_t)p * NN + y) * 3 + 2];
        dG[((size_t)p * NN + x) * NN + y] =
            sqrtf(fmaf(dx, dx, fmaf(dy, dy, fmaf(dz, dz, 1e-12f))));
    }
}

// ---------------------------------------------------------------------------
// k1T (grid=1536, 256 thr): block bid computes the FULL T[x=bid>>1] into its
// PRIVATE copy Tg[bid][2048]  ->  producer XCD == consumer XCD (bid%8).
// Thread tid owns c = tid*8..+7. W rows stream coalesced (wave = 2 KB/row).
// Same i-sequential fp32 fma order as all passing rounds.
// ---------------------------------------------------------------------------
__global__ __launch_bounds__(256) void k1T(const float* __restrict__ hid,
                                           const float* __restrict__ W,
                                           float* __restrict__ Tg) {
    const int bid = blockIdx.x;
    const int x   = bid >> 1;
    const int tid = threadIdx.x;
    const int cb  = tid * 8;

    float a[8];
#pragma unroll
    for (int q = 0; q < 8; ++q) a[q] = 0.0f;

#pragma unroll 4
    for (int i = 0; i < 64; ++i) {
        const float hv = hid[(size_t)x * 64 + i];   // block-uniform
        const float4 w0 = *reinterpret_cast<const float4*>(&W[(size_t)i * 2048 + cb]);
        const float4 w1 = *reinterpret_cast<const float4*>(&W[(size_t)i * 2048 + cb + 4]);
        a[0] = fmaf(hv, w0.x, a[0]); a[1] = fmaf(hv, w0.y, a[1]);
        a[2] = fmaf(hv, w0.z, a[2]); a[3] = fmaf(hv, w0.w, a[3]);
        a[4] = fmaf(hv, w1.x, a[4]); a[5] = fmaf(hv, w1.y, a[5]);
        a[6] = fmaf(hv, w1.z, a[6]); a[7] = fmaf(hv, w1.w, a[7]);
    }

    float4 o0, o1;
    o0.x = a[0]; o0.y = a[1]; o0.z = a[2]; o0.w = a[3];
    o1.x = a[4]; o1.y = a[5]; o1.z = a[6]; o1.w = a[7];
    *reinterpret_cast<float4*>(&Tg[(size_t)bid * 2048 + cb])     = o0;
    *reinterpret_cast<float4*>(&Tg[(size_t)bid * 2048 + cb + 4]) = o1;
}

// ---------------------------------------------------------------------------
// k1F (grid=12, 256 thr): bf16 hi/lo A-fragment planes of hid (R7-proven).
//   element (y,j): t=y>>4, r=y&15, kh=j>>5, g=(j>>3)&3, e=j&7
//   hbX[ t*1024 + kh*512 + (g*16+r)*8 + e ]
// Shared read-only by all k2 blocks; 192 KB total, L2-replicated.
// ---------------------------------------------------------------------------
__global__ __launch_bounds__(256) void k1F(const float* __restrict__ hid,
                                           unsigned short* __restrict__ hbHi,
                                           unsigned short* __restrict__ hbLo) {
    const int b   = blockIdx.x;
    const int tid = threadIdx.x;
    const int base = b * 4096 + tid * 16;   // flat (y*64+j)
    const int y  = base >> 6;
    const int j0 = base & 63;
    const int t  = y >> 4;
    const int r  = y & 15;
    float hv[16];
#pragma unroll
    for (int c = 0; c < 4; ++c) {
        const float4 v = *reinterpret_cast<const float4*>(&hid[(size_t)y * 64 + j0 + c * 4]);
        hv[c * 4 + 0] = v.x; hv[c * 4 + 1] = v.y; hv[c * 4 + 2] = v.z; hv[c * 4 + 3] = v.w;
    }
#pragma unroll
    for (int n = 0; n < 16; ++n) {
        const int j  = j0 + n;
        const int kh = j >> 5;
        const int g  = (j >> 3) & 3;
        const int e  = j & 7;
        const int idx = t * 1024 + kh * 512 + (g * 16 + r) * 8 + e;
        const unsigned short hi = f2bf(hv[n]);
        const float lo = hv[n] - bf2f(hi);
        hbHi[idx] = hi;
        hbLo[idx] = f2bf(lo);
    }
}

// ---------------------------------------------------------------------------
// k2 (grid=1536, 256 thr = 4 waves): R6/R7-proven kernel (23 us warm).
// ONLY change: Tg indexed by bid (private XCD-local copy).
// ---------------------------------------------------------------------------
__global__ __launch_bounds__(256, 2) void k2_main(const float* __restrict__ b_rbf,
                                                  const float* __restrict__ Tg,
                                                  const unsigned short* __restrict__ hbHi,
                                                  const unsigned short* __restrict__ hbLo,
                                                  const float* __restrict__ dG,
                                                  float* __restrict__ partials,
                                                  unsigned* __restrict__ ctr,
                                                  const float* __restrict__ weight,
                                                  const float* __restrict__ bias_,
                                                  float* __restrict__ out) {
    const int bid = blockIdx.x;
    const int x   = bid >> 1;
    const int h   = bid & 1;
    const int tid = threadIdx.x;
    const int l   = tid & 63;
    const int wv  = tid >> 6;
    const int g   = l >> 4;
    const int c16 = l & 15;

    __shared__ unsigned short bh_s[2048];  // 4 KB  B-frag hi
    __shared__ unsigned short bl_s[2048];  // 4 KB  B-frag lo
    __shared__ float red16[16];
    __shared__ unsigned flagS;

    // ---- prologue: Tg[bid] -> bf16 hi/lo B-fragments in LDS ----
    {
        const float4 t0 = *reinterpret_cast<const float4*>(&Tg[(size_t)bid * 2048 + tid * 8]);
        const float4 t1 = *reinterpret_cast<const float4*>(&Tg[(size_t)bid * 2048 + tid * 8 + 4]);
        float tv[8];
        tv[0] = t0.x; tv[1] = t0.y; tv[2] = t0.z; tv[3] = t0.w;
        tv[4] = t1.x; tv[5] = t1.y; tv[6] = t1.z; tv[7] = t1.w;
        const int j    = tid >> 2;
        const int kh   = tid >> 7;
        const int jg   = (tid >> 5) & 3;
        const int e    = j & 7;
        const int st   = (tid >> 1) & 1;
        const int srb  = (tid & 1) * 8;
        const int base = (st * 2 + kh) * 512 + (jg * 16 + srb) * 8 + e;
#pragma unroll
        for (int q = 0; q < 8; ++q) {
            const unsigned short hi = f2bf(tv[q]);
            const float lo = tv[q] - bf2f(hi);
            bh_s[base + q * 8] = hi;
            bl_s[base + q * 8] = f2bf(lo);
        }
    }
    __syncthreads();   // only barrier before reduction

    const float mu0 = (float)(c16)      * MU_STEP;
    const float mu1 = (float)(16 + c16) * MU_STEP;
    const float A0 = -2.0f * NEG2C * mu0, B0v = NEG2C * mu0 * mu0;
    const float A1 = -2.0f * NEG2C * mu1, B1v = NEG2C * mu1 * mu1;
    const float brbf0 = b_rbf[c16];
    const float brbf1 = b_rbf[16 + c16];

    float e0 = 0.0f, e1 = 0.0f, e2 = 0.0f, e3 = 0.0f;

    for (int k = 0; k < 6; ++k) {
        const int t  = h * 24 + (k << 2) + wv;   // y-tile 0..47
        const int ab = t * 1024 + l * 8;
        const int yb = t * 16 + g * 4;
        const size_t dbase = (size_t)x * NN + yb;

        const bf16x8 aH0 = *reinterpret_cast<const bf16x8*>(&hbHi[ab]);
        const bf16x8 aH1 = *reinterpret_cast<const bf16x8*>(&hbHi[ab + 512]);
        const bf16x8 aL0 = *reinterpret_cast<const bf16x8*>(&hbLo[ab]);
        const bf16x8 aL1 = *reinterpret_cast<const bf16x8*>(&hbLo[ab + 512]);
        const float4 dd0 = *reinterpret_cast<const float4*>(&dG[0 * (size_t)NN * NN + dbase]);
        const float4 dd1 = *reinterpret_cast<const float4*>(&dG[1 * (size_t)NN * NN + dbase]);
        const float4 dd2 = *reinterpret_cast<const float4*>(&dG[2 * (size_t)NN * NN + dbase]);
        const float4 dd3 = *reinterpret_cast<const float4*>(&dG[3 * (size_t)NN * NN + dbase]);

        const bf16x8 bH00 = *reinterpret_cast<const bf16x8*>(&bh_s[l * 8]);
        const bf16x8 bH01 = *reinterpret_cast<const bf16x8*>(&bh_s[512 + l * 8]);
        const bf16x8 bH10 = *reinterpret_cast<const bf16x8*>(&bh_s[1024 + l * 8]);
        const bf16x8 bH11 = *reinterpret_cast<const bf16x8*>(&bh_s[1536 + l * 8]);
        const bf16x8 bL00 = *reinterpret_cast<const bf16x8*>(&bl_s[l * 8]);
        const bf16x8 bL01 = *reinterpret_cast<const bf16x8*>(&bl_s[512 + l * 8]);
        const bf16x8 bL10 = *reinterpret_cast<const bf16x8*>(&bl_s[1024 + l * 8]);
        const bf16x8 bL11 = *reinterpret_cast<const bf16x8*>(&bl_s[1536 + l * 8]);

        f32x4 acc0 = {0.0f, 0.0f, 0.0f, 0.0f};
        f32x4 acc1 = {0.0f, 0.0f, 0.0f, 0.0f};
        acc0 = __builtin_amdgcn_mfma_f32_16x16x32_bf16(aH0, bH00, acc0, 0, 0, 0);
        acc1 = __builtin_amdgcn_mfma_f32_16x16x32_bf16(aH0, bH10, acc1, 0, 0, 0);
        acc0 = __builtin_amdgcn_mfma_f32_16x16x32_bf16(aH1, bH01, acc0, 0, 0, 0);
        acc1 = __builtin_amdgcn_mfma_f32_16x16x32_bf16(aH1, bH11, acc1, 0, 0, 0);
        acc0 = __builtin_amdgcn_mfma_f32_16x16x32_bf16(aH0, bL00, acc0, 0, 0, 0);
        acc1 = __builtin_amdgcn_mfma_f32_16x16x32_bf16(aH0, bL10, acc1, 0, 0, 0);
        acc0 = __builtin_amdgcn_mfma_f32_16x16x32_bf16(aH1, bL01, acc0, 0, 0, 0);
        acc1 = __builtin_amdgcn_mfma_f32_16x16x32_bf16(aH1, bL11, acc1, 0, 0, 0);
        acc0 = __builtin_amdgcn_mfma_f32_16x16x32_bf16(aL0, bH00, acc0, 0, 0, 0);
        acc1 = __builtin_amdgcn_mfma_f32_16x16x32_bf16(aL0, bH10, acc1, 0, 0, 0);
        acc0 = __builtin_amdgcn_mfma_f32_16x16x32_bf16(aL1, bH01, acc0, 0, 0, 0);
        acc1 = __builtin_amdgcn_mfma_f32_16x16x32_bf16(aL1, bH11, acc1, 0, 0, 0);

        const float ab00 = acc0[0] + brbf0, ab01 = acc0[1] + brbf0,
                    ab02 = acc0[2] + brbf0, ab03 = acc0[3] + brbf0;
        const float ab10 = acc1[0] + brbf1, ab11 = acc1[1] + brbf1,
                    ab12 = acc1[2] + brbf1, ab13 = acc1[3] + brbf1;

#pragma unroll
        for (int p = 0; p < PP; ++p) {
            const float4 dd = (p == 0) ? dd0 : (p == 1) ? dd1 : (p == 2) ? dd2 : dd3;
            float* ep = (p == 0) ? &e0 : (p == 1) ? &e1 : (p == 2) ? &e2 : &e3;
            float accp = 0.0f;
#pragma unroll
            for (int r = 0; r < 4; ++r) {
                if (yb + r == x) continue;     // diagonal mask
                const float d   = (r == 0) ? dd.x : (r == 1) ? dd.y : (r == 2) ? dd.z : dd.w;
                const float d2c = d * d * NEG2C;
                const float w0 = __builtin_exp2f(fmaf(A0, d, d2c + B0v));
                const float w1 = __builtin_exp2f(fmaf(A1, d, d2c + B1v));
                const float a0 = (r == 0) ? ab00 : (r == 1) ? ab01 : (r == 2) ? ab02 : ab03;
                const float a1 = (r == 0) ? ab10 : (r == 1) ? ab11 : (r == 2) ? ab12 : ab13;
                accp = fmaf(a0, w0, accp);
                accp = fmaf(a1, w1, accp);
            }
            *ep += accp;
        }
    }

    // ---- deterministic reduction ----
    float e[PP] = {e0, e1, e2, e3};
#pragma unroll
    for (int off = 1; off < 64; off <<= 1)
#pragma unroll
        for (int p = 0; p < PP; ++p) e[p] += __shfl_xor(e[p], off, 64);

    if (l == 0) {
#pragma unroll
        for (int p = 0; p < PP; ++p) red16[wv * 4 + p] = e[p];
    }
    __syncthreads();
    if (tid < 4) {
        const float s = red16[0 * 4 + tid] + red16[1 * 4 + tid] +
                        red16[2 * 4 + tid] + red16[3 * 4 + tid];
        partials[(size_t)bid * 4 + tid] = s;
    }

    // ---- fused final reduction: last block sums all partials ----
    __threadfence();
    __syncthreads();
    if (tid == 0) {
        const unsigned old = atomicAdd(ctr, 1u);
        flagS = (old == NB2 - 1) ? 1u : 0u;
    }
    __syncthreads();
    if (flagS) {
        __threadfence();
        const int p    = tid >> 6;
        const int lane = tid & 63;
        float s = 0.0f;
#pragma unroll
        for (int kk = 0; kk < 24; ++kk)
            s += partials[(size_t)(lane * 24 + kk) * 4 + p];
#pragma unroll
        for (int off = 1; off < 64; off <<= 1) s += __shfl_xor(s, off, 64);
        if (lane == 0)
            out[p] = s * (1.0f / 18874368.0f) * weight[0] + bias_[0];
    }
}

// ---------------------------------------------------------------------------
// Fallback path (ws too small): self-contained fp32 kernel + final reduce
// ---------------------------------------------------------------------------
__global__ __launch_bounds__(256, 4) void k2_fb(const float* __restrict__ hid,
                                                const float* __restrict__ coords,
                                                const float* __restrict__ W,
                                                const float* __restrict__ b_rbf,
                                                float* __restrict__ partials) {
    const int x   = blockIdx.x;
    const int tid = threadIdx.x;
    const int ty  = tid & 63;
    const int ts  = tid >> 6;

    __shared__ float pool[2048 + 64 * 128];
    float* T_l = pool;
    float* h_t = pool + 2048;

    {
        float a0[4] = {0, 0, 0, 0}, a1[4] = {0, 0, 0, 0};
        for (int i = 0; i < 64; ++i) {
            const float hv = hid[(size_t)x * 64 + i];
            const float4 w0 = *reinterpret_cast<const float4*>(&W[(size_t)i * 2048 + tid * 4]);
            const float4 w1 = *reinterpret_cast<const float4*>(&W[(size_t)i * 2048 + 1024 + tid * 4]);
            a0[0] += hv * w0.x; a0[1] += hv * w0.y; a0[2] += hv * w0.z; a0[3] += hv * w0.w;
            a1[0] += hv * w1.x; a1[1] += hv * w1.y; a1[2] += hv * w1.z; a1[3] += hv * w1.w;
        }
        T_l[tid * 4 + 0] = a0[0]; T_l[tid * 4 + 1] = a0[1];
        T_l[tid * 4 + 2] = a0[2]; T_l[tid * 4 + 3] = a0[3];
        T_l[1024 + tid * 4 + 0] = a1[0]; T_l[1024 + tid * 4 + 1] = a1[1];
        T_l[1024 + tid * 4 + 2] = a1[2]; T_l[1024 + tid * 4 + 3] = a1[3];
    }

    float mu_reg[8], b_reg[8];
#pragma unroll
    for (int u = 0; u < 8; ++u) {
        const int s = ts * 8 + u;
        mu_reg[u] = (float)s * MU_STEP;
        b_reg[u]  = b_rbf[s];
    }
    float cx[PP][3];
#pragma unroll
    for (int p = 0; p < PP; ++p)
#pragma unroll
        for (int c = 0; c < 3; ++c)
            cx[p][c] = coords[(size_t)p * NN * 3 + (size_t)x * 3 + c];

    float e[PP] = {0.0f, 0.0f, 0.0f, 0.0f};
    const int srow = tid >> 1;
    const int r0   = (tid & 1) * 8;
    const int hoff = ty * 2;
    const int toff = ts * 8;

    for (int ch = 0; ch < 6; ++ch) {
        const int y0 = ch * 128;
        __syncthreads();
        {
            const int y = y0 + srow;
#pragma unroll
            for (int r = 0; r < 8; ++r) {
                const float4 v = *reinterpret_cast<const float4*>(
                    &hid[(size_t)y * 64 + (r0 + r) * 4]);
                const int j = (r0 + r) * 4;
                h_t[(j + 0) * 128 + srow] = v.x;
                h_t[(j + 1) * 128 + srow] = v.y;
                h_t[(j + 2) * 128 + srow] = v.z;
                h_t[(j + 3) * 128 + srow] = v.w;
            }
        }
        __syncthreads();

        float acc[2][8];
#pragma unroll
        for (int i = 0; i < 2; ++i)
#pragma unroll
            for (int u = 0; u < 8; ++u) acc[i][u] = 0.0f;

#pragma unroll 4
        for (int j = 0; j < 64; ++j) {
            const float h0 = h_t[j * 128 + hoff];
            const float h1 = h_t[j * 128 + hoff + 1];
            const float4 t0 = *reinterpret_cast<const float4*>(&T_l[j * 32 + toff]);
            const float4 t1 = *reinterpret_cast<const float4*>(&T_l[j * 32 + toff + 4]);
            acc[0][0] += h0 * t0.x; acc[0][1] += h0 * t0.y; acc[0][2] += h0 * t0.z; acc[0][3] += h0 * t0.w;
            acc[0][4] += h0 * t1.x; acc[0][5] += h0 * t1.y; acc[0][6] += h0 * t1.z; acc[0][7] += h0 * t1.w;
            acc[1][0] += h1 * t0.x; acc[1][1] += h1 * t0.y; acc[1][2] += h1 * t0.z; acc[1][3] += h1 * t0.w;
            acc[1][4] += h1 * t1.x; acc[1][5] += h1 * t1.y; acc[1][6] += h1 * t1.z; acc[1][7] += h1 * t1.w;
        }

        float ab[2][8];
#pragma unroll
        for (int i = 0; i < 2; ++i)
#pragma unroll
            for (int u = 0; u < 8; ++u) ab[i][u] = acc[i][u] + b_reg[u];

#pragma unroll
        for (int i = 0; i < 2; ++i) {
            const int y = y0 + hoff + i;
            if (y == x) continue;
#pragma unroll
            for (int p = 0; p < PP; ++p) {
                const float dx = cx[p][0] - coords[(size_t)p * NN * 3 + (size_t)y * 3 + 0];
                const float dy = cx[p][1] - coords[(size_t)p * NN * 3 + (size_t)y * 3 + 1];
                const float dz = cx[p][2] - coords[(size_t)p * NN * 3 + (size_t)y * 3 + 2];
                const float d  = sqrtf(dx * dx + dy * dy + dz * dz + 1e-12f);
                float ep = 0.0f;
#pragma unroll
                for (int u = 0; u < 8; ++u) {
                    const float t = d - mu_reg[u];
                    const float w = __builtin_exp2f(t * t * NEG2C);
                    ep = fmaf(ab[i][u], w, ep);
                }
                e[p] += ep;
            }
        }
    }

#pragma unroll
    for (int off = 1; off < 64; off <<= 1)
#pragma unroll
        for (int p = 0; p < PP; ++p) e[p] += __shfl_xor(e[p], off, 64);

    __syncthreads();
    if (ty == 0) {
#pragma unroll
        for (int p = 0; p < PP; ++p) pool[ts * 4 + p] = e[p];
    }
    __syncthreads();
    if (tid < 4) {
        const float s = pool[0 * 4 + tid] + pool[1 * 4 + tid] +
                        pool[2 * 4 + tid] + pool[3 * 4 + tid];
        partials[(size_t)x * 4 + tid] = s;
    }
}

__global__ __launch_bounds__(256) void k3_final(const float* __restrict__ partials,
                                                const float* __restrict__ weight,
                                                const float* __restrict__ bias_,
                                                float* __restrict__ out) {
    const int p    = threadIdx.x >> 6;
    const int lane = threadIdx.x & 63;
    float s = 0.0f;
#pragma unroll
    for (int k = 0; k < 12; ++k) s += partials[(size_t)(lane * 12 + k) * 4 + p];
#pragma unroll
    for (int off = 1; off < 64; off <<= 1) s += __shfl_xor(s, off, 64);
    if (lane == 0)
        out[p] = s * (1.0f / 18874368.0f) * weight[0] + bias_[0];
}

// ---------------------------------------------------------------------------
extern "C" void kernel_launch(void* const* d_in, const int* in_sizes, int n_in,
                              void* d_out, int out_size, void* d_ws, size_t ws_size,
                              hipStream_t stream) {
    const float* hid    = (const float*)d_in[0];
    const float* coords = (const float*)d_in[1];
    const float* W      = (const float*)d_in[2];
    const float* b_rbf  = (const float*)d_in[3];
    const float* weight = (const float*)d_in[4];
    const float* bias_  = (const float*)d_in[5];
    float* out = (float*)d_out;

    const size_t T_BYTES    = (size_t)NB2 * 2048 * sizeof(float);         // 12.6 MB (dup)
    const size_t HB_BYTES   = (size_t)48 * 1024 * sizeof(unsigned short); // 96 KB/plane
    const size_t D_BYTES    = (size_t)PP * NN * NN * sizeof(float);       // 9.44 MB
    const size_t PART_BYTES = (size_t)NB2 * 4 * sizeof(float);            // 24.6 KB
    const size_t TOTAL = T_BYTES + 2 * HB_BYTES + D_BYTES + PART_BYTES + 64;
    const bool use_ws = ws_size >= TOTAL;

    char* w = (char*)d_ws;
    float*          Tg       = (float*)w;
    unsigned short* hbHi     = (unsigned short*)(w + T_BYTES);
    unsigned short* hbLo     = (unsigned short*)(w + T_BYTES + HB_BYTES);
    float*          dG       = (float*)(w + T_BYTES + 2 * HB_BYTES);
    float*          partials = use_ws ? (float*)(w + T_BYTES + 2 * HB_BYTES + D_BYTES)
                                      : (float*)d_ws;
    unsigned*       ctr      = (unsigned*)(w + T_BYTES + 2 * HB_BYTES + D_BYTES + PART_BYTES);

    if (use_ws) {
        kD6<<<PP * NB2, 128, 0, stream>>>(coords, dG, ctr);
        k1F<<<12, 256, 0, stream>>>(hid, hbHi, hbLo);
        k1T<<<NB2, 256, 0, stream>>>(hid, W, Tg);
        k2_main<<<NB2, 256, 0, stream>>>(b_rbf, Tg, hbHi, hbLo, dG, partials,
                                         ctr, weight, bias_, out);
    } else {
        k2_fb<<<NN, 256, 0, stream>>>(hid, coords, W, b_rbf, partials);
        k3_final<<<1, 256, 0, stream>>>(partials, weight, bias_, out);
    }
}